// Round 1
// baseline (2831.708 us; speedup 1.0000x reference)
//
#include <hip/hip_runtime.h>
#include <math.h>

// ---------- types ----------
typedef unsigned short u16;
typedef __attribute__((ext_vector_type(8))) short short8;     // 8x16-bit raw (bf16 bits)
typedef __attribute__((ext_vector_type(8))) _Float16 half8;   // 8x fp16
typedef __attribute__((ext_vector_type(4))) float f32x4;

__device__ inline u16 f32_to_bf16_rne(float f){
    unsigned int u = __float_as_uint(f);
    unsigned int r = (u + 0x7FFFu + ((u >> 16) & 1u)) >> 16;
    return (u16)r;
}
__device__ inline float bf16_to_f32(u16 h){ return __uint_as_float(((unsigned int)h) << 16); }
__device__ inline u16 h2b(_Float16 h){ union { _Float16 f; u16 u; } x; x.f = h; return x.u; }

// ---------- constants ----------
#define TT 2048      // tokens
#define DD 2048      // model dim
#define SS 1024      // seq len
#define NH 16        // heads

#define EPI_F32     0
#define EPI_BF16    1
#define EPI_RES     2
#define EPI_SILUMUL 3
#define EPI_F16PAIR 4

// =====================================================================
// Generic 128x128 MFMA GEMM.  C[M,N] = A[M,K] @ B[K,N]
// A: 16-bit planes (bf16 bits, or fp16 hi/lo pair when PREC).
// B: f32 row-major, staged+converted to LDS each K-step.
// Expert grouping: e=blockIdx.z, rows counted by cnt[e], A rows optionally
// gathered via token list; C rows written at offs[e]+r.
// =====================================================================
template<int EPI, bool PREC>
__global__ __launch_bounds__(256) void gemm_k(
    const void* A0v, const void* A1v, int lda,
    const float* __restrict__ B, int ldb, long long bstr,
    int M, int N, int K,
    const int* offs, const int* cnt, const int* gather,
    void* C0, void* C1, int ldc,
    const void* aux)
{
    __shared__ u16 AsH[128][40];
    __shared__ u16 AsL[PREC ? 128 : 1][PREC ? 40 : 1];
    __shared__ u16 BsH[32][132];
    __shared__ u16 BsL[PREC ? 32 : 1][PREC ? 132 : 1];

    int tid  = threadIdx.x;
    int lane = tid & 63;
    int wv   = tid >> 6;
    int wm = (wv >> 1) * 64, wn = (wv & 1) * 64;

    int e    = blockIdx.z;
    int base = offs ? offs[e] : 0;
    int mc   = cnt ? cnt[e] : M;
    int m0   = blockIdx.y * 128;
    if (m0 >= mc) return;
    int n0 = blockIdx.x * 128;
    const float* Bp = B + (long long)e * bstr;
    const u16* A0 = (const u16*)A0v;
    const u16* A1 = (const u16*)A1v;

    int r0 = tid >> 2, r1 = r0 + 64, c0 = tid & 3;
    long long arow0 = -1, arow1 = -1;
    if (m0 + r0 < mc) arow0 = gather ? (long long)gather[base + m0 + r0] : (long long)(base + m0 + r0);
    if (m0 + r1 < mc) arow1 = gather ? (long long)gather[base + m0 + r1] : (long long)(base + m0 + r1);

    f32x4 acc[4][4];
#pragma unroll
    for (int i = 0; i < 4; i++)
#pragma unroll
        for (int j = 0; j < 4; j++) { f32x4 z = {0.f,0.f,0.f,0.f}; acc[i][j] = z; }

    short8 zer = {0,0,0,0,0,0,0,0};

    for (int kt = 0; kt < K; kt += 32) {
        __syncthreads();
        // ---- stage A (16-bit, vector) ----
        {
            short8 v0 = (arow0 >= 0) ? *(const short8*)(A0 + arow0 * lda + kt + c0 * 8) : zer;
            *(short8*)&AsH[r0][c0 * 8] = v0;
            short8 v1 = (arow1 >= 0) ? *(const short8*)(A0 + arow1 * lda + kt + c0 * 8) : zer;
            *(short8*)&AsH[r1][c0 * 8] = v1;
            if (PREC) {
                short8 w0 = (arow0 >= 0) ? *(const short8*)(A1 + arow0 * lda + kt + c0 * 8) : zer;
                *(short8*)&AsL[r0][c0 * 8] = w0;
                short8 w1 = (arow1 >= 0) ? *(const short8*)(A1 + arow1 * lda + kt + c0 * 8) : zer;
                *(short8*)&AsL[r1][c0 * 8] = w1;
            }
        }
        // ---- stage B (f32 -> 16-bit convert) : 32x128 = 1024 float4 ----
#pragma unroll
        for (int it = 0; it < 4; ++it) {
            int idx = it * 256 + tid;
            int br = idx >> 5, cc = idx & 31;
            int col = n0 + cc * 4;
            float vv[4] = {0.f, 0.f, 0.f, 0.f};
            if (col + 3 < N) {
                float4 v = *(const float4*)(Bp + (long long)(kt + br) * ldb + col);
                vv[0] = v.x; vv[1] = v.y; vv[2] = v.z; vv[3] = v.w;
            } else {
                const float* p = Bp + (long long)(kt + br) * ldb;
#pragma unroll
                for (int q2 = 0; q2 < 4; q2++) vv[q2] = (col + q2 < N) ? p[col + q2] : 0.f;
            }
            if (PREC) {
#pragma unroll
                for (int q2 = 0; q2 < 4; q2++) {
                    _Float16 hi = (_Float16)vv[q2];
                    BsH[br][cc * 4 + q2] = h2b(hi);
                    BsL[br][cc * 4 + q2] = h2b((_Float16)(vv[q2] - (float)hi));
                }
            } else {
#pragma unroll
                for (int q2 = 0; q2 < 4; q2++) BsH[br][cc * 4 + q2] = f32_to_bf16_rne(vv[q2]);
            }
        }
        __syncthreads();
        // ---- compute ----
        if (PREC) {
            half8 ah[4], al[4];
#pragma unroll
            for (int i = 0; i < 4; i++) {
                ah[i] = *(const half8*)&AsH[wm + i * 16 + (lane & 15)][(lane >> 4) * 8];
                al[i] = *(const half8*)&AsL[wm + i * 16 + (lane & 15)][(lane >> 4) * 8];
            }
#pragma unroll
            for (int j = 0; j < 4; j++) {
                int colb = wn + j * 16 + (lane & 15);
                half8 bh, bl;
#pragma unroll
                for (int u = 0; u < 8; u++) {
                    bh[u] = *(const _Float16*)&BsH[(lane >> 4) * 8 + u][colb];
                    bl[u] = *(const _Float16*)&BsL[(lane >> 4) * 8 + u][colb];
                }
#pragma unroll
                for (int i = 0; i < 4; i++) {
                    acc[i][j] = __builtin_amdgcn_mfma_f32_16x16x32_f16(ah[i], bh, acc[i][j], 0, 0, 0);
                    acc[i][j] = __builtin_amdgcn_mfma_f32_16x16x32_f16(ah[i], bl, acc[i][j], 0, 0, 0);
                    acc[i][j] = __builtin_amdgcn_mfma_f32_16x16x32_f16(al[i], bh, acc[i][j], 0, 0, 0);
                }
            }
        } else {
            short8 af[4];
#pragma unroll
            for (int i = 0; i < 4; i++)
                af[i] = *(const short8*)&AsH[wm + i * 16 + (lane & 15)][(lane >> 4) * 8];
#pragma unroll
            for (int j = 0; j < 4; j++) {
                int colb = wn + j * 16 + (lane & 15);
                short8 bfr;
#pragma unroll
                for (int u = 0; u < 8; u++) bfr[u] = (short)BsH[(lane >> 4) * 8 + u][colb];
#pragma unroll
                for (int i = 0; i < 4; i++)
                    acc[i][j] = __builtin_amdgcn_mfma_f32_16x16x32_bf16(af[i], bfr, acc[i][j], 0, 0, 0);
            }
        }
    }
    // ---- epilogue ----
#pragma unroll
    for (int i = 0; i < 4; i++) {
        int rbase = m0 + wm + i * 16 + ((lane >> 4) << 2);
#pragma unroll
        for (int j = 0; j < 4; j++) {
            int col = n0 + wn + j * 16 + (lane & 15);
            if (col >= N) continue;
#pragma unroll
            for (int r = 0; r < 4; r++) {
                int rr = rbase + r;
                if (rr >= mc) continue;
                long long cidx = (long long)(base + rr) * ldc + col;
                float v = acc[i][j][r];
                if (EPI == EPI_F32)      ((float*)C0)[cidx] = v;
                else if (EPI == EPI_BF16) ((u16*)C0)[cidx] = f32_to_bf16_rne(v);
                else if (EPI == EPI_RES)  ((float*)C0)[cidx] = v + ((const float*)aux)[cidx];
                else if (EPI == EPI_SILUMUL) {
                    float h1v = bf16_to_f32(((const u16*)aux)[cidx]);
                    float g = h1v / (1.f + __expf(-h1v)) * v;
                    ((u16*)C0)[cidx] = f32_to_bf16_rne(g);
                } else { // F16PAIR
                    _Float16 hh = (_Float16)v;
                    ((u16*)C0)[cidx] = h2b(hh);
                    ((u16*)C1)[cidx] = h2b((_Float16)(v - (float)hh));
                }
            }
        }
    }
}

// =====================================================================
// cos/sin table: [S][32]
// =====================================================================
__global__ void costab_k(const int* sp, float* ct, float* st){
    int idx = blockIdx.x * 256 + threadIdx.x;
    if (idx >= SS * 32) return;
    int i = idx & 31, s = idx >> 5;
    float inv = powf(10000.0f, -(float)i / 32.0f);
    float a = (float)(sp[0] + s) * inv;
    ct[idx] = cosf(a);
    st[idx] = sinf(a);
}

// =====================================================================
// rmsnorm: row of 2048 f32 -> MODE 0: fp16 hi/lo planes; MODE 1: bf16
// =====================================================================
template<int MODE>
__global__ __launch_bounds__(256) void rms_k(const float* __restrict__ x, const float* __restrict__ w,
                                             u16* o0, u16* o1){
    int t = blockIdx.x, tid = threadIdx.x;
    const float* row = x + (long long)t * DD;
    float4 v0 = *(const float4*)(row + tid * 4);
    float4 v1 = *(const float4*)(row + 1024 + tid * 4);
    float ss = v0.x*v0.x + v0.y*v0.y + v0.z*v0.z + v0.w*v0.w
             + v1.x*v1.x + v1.y*v1.y + v1.z*v1.z + v1.w*v1.w;
#pragma unroll
    for (int d = 1; d < 64; d <<= 1) ss += __shfl_xor(ss, d, 64);
    __shared__ float red[4];
    if ((tid & 63) == 0) red[tid >> 6] = ss;
    __syncthreads();
    float sc = rsqrtf((red[0] + red[1] + red[2] + red[3]) / (float)DD + 1e-6f);
    float a[8];
    a[0]=v0.x; a[1]=v0.y; a[2]=v0.z; a[3]=v0.w; a[4]=v1.x; a[5]=v1.y; a[6]=v1.z; a[7]=v1.w;
#pragma unroll
    for (int q2 = 0; q2 < 8; q2++) {
        int d = (q2 < 4) ? (tid * 4 + q2) : (1024 + tid * 4 + (q2 - 4));
        float y = a[q2] * sc * w[d];
        if (MODE == 0) {
            _Float16 hh = (_Float16)y;
            o0[(long long)t * DD + d] = h2b(hh);
            o1[(long long)t * DD + d] = h2b((_Float16)(y - (float)hh));
        } else {
            o0[(long long)t * DD + d] = f32_to_bf16_rne(y);
        }
    }
}

// =====================================================================
// kvprep: rmsnorm(kv[:,:512]) -> fp16 pair; rope(kv[:,512:576]) -> fp16 pair
// =====================================================================
__global__ __launch_bounds__(256) void kvprep_k(const float* __restrict__ kv, const float* __restrict__ kw,
    const float* __restrict__ ct, const float* __restrict__ st,
    u16* lath, u16* latl, u16* kpeh, u16* kpel){
    int t = blockIdx.x, tid = threadIdx.x;
    const float* row = kv + (long long)t * 576;
    float x0 = row[tid], x1 = row[256 + tid];
    float ss = x0 * x0 + x1 * x1;
#pragma unroll
    for (int d = 1; d < 64; d <<= 1) ss += __shfl_xor(ss, d, 64);
    __shared__ float red[4];
    if ((tid & 63) == 0) red[tid >> 6] = ss;
    __syncthreads();
    float sc = rsqrtf((red[0] + red[1] + red[2] + red[3]) / 512.f + 1e-6f);
    float y0 = x0 * sc * kw[tid], y1 = x1 * sc * kw[256 + tid];
    _Float16 h0 = (_Float16)y0, h1 = (_Float16)y1;
    lath[(long long)t * 512 + tid] = h2b(h0);
    latl[(long long)t * 512 + tid] = h2b((_Float16)(y0 - (float)h0));
    lath[(long long)t * 512 + 256 + tid] = h2b(h1);
    latl[(long long)t * 512 + 256 + tid] = h2b((_Float16)(y1 - (float)h1));
    if (tid < 32) {
        int s = t & (SS - 1);
        float a0 = row[512 + 2 * tid], a1 = row[513 + 2 * tid];
        float c = ct[s * 32 + tid], sn = st[s * 32 + tid];
        float r0 = a0 * c - a1 * sn, r1 = a0 * sn + a1 * c;
        _Float16 p0 = (_Float16)r0, p1 = (_Float16)r1;
        kpeh[(long long)t * 64 + 2 * tid]     = h2b(p0);
        kpel[(long long)t * 64 + 2 * tid]     = h2b((_Float16)(r0 - (float)p0));
        kpeh[(long long)t * 64 + 2 * tid + 1] = h2b(p1);
        kpel[(long long)t * 64 + 2 * tid + 1] = h2b((_Float16)(r1 - (float)p1));
    }
}

// =====================================================================
// qprep: q planes [T][3072] -> q_r planes [BH][S][192] with RoPE on d>=128
// =====================================================================
__global__ void qprep_k(const u16* __restrict__ qh, const u16* __restrict__ ql,
    const float* __restrict__ ct, const float* __restrict__ st, u16* qrh, u16* qrl){
    int idx = blockIdx.x * 256 + threadIdx.x;
    int p = idx % 96; int rest = idx / 96;
    int s = rest & (SS - 1); int bh = rest >> 10;
    if (bh >= 32) return;
    int b = bh >> 4, hh = bh & 15;
    long long t = (long long)b * SS + s;
    long long si = t * 3072 + hh * 192 + 2 * p;
    float a0 = (float)*(const _Float16*)&qh[si]     + (float)*(const _Float16*)&ql[si];
    float a1 = (float)*(const _Float16*)&qh[si + 1] + (float)*(const _Float16*)&ql[si + 1];
    if (p >= 64) {
        int i = p - 64;
        float c = ct[s * 32 + i], sn = st[s * 32 + i];
        float r0 = a0 * c - a1 * sn, r1 = a0 * sn + a1 * c;
        a0 = r0; a1 = r1;
    }
    long long di = ((long long)bh * SS + s) * 192 + 2 * p;
    _Float16 h0 = (_Float16)a0, h1 = (_Float16)a1;
    qrh[di] = h2b(h0); qrl[di] = h2b((_Float16)(a0 - (float)h0));
    qrh[di + 1] = h2b(h1); qrl[di + 1] = h2b((_Float16)(a1 - (float)h1));
}

// =====================================================================
// kprep: k_r planes [BH][S][192]: nope from kvb, pe (already roped, shared across h)
// =====================================================================
__global__ void kprep_k(const u16* __restrict__ kvbh, const u16* __restrict__ kvbl,
    const u16* __restrict__ kpeh, const u16* __restrict__ kpel, u16* krh, u16* krl){
    int idx = blockIdx.x * 256 + threadIdx.x;
    int d = idx % 192; int rest = idx / 192;
    int s = rest & (SS - 1); int bh = rest >> 10;
    if (bh >= 32) return;
    int b = bh >> 4, hh = bh & 15;
    long long t = (long long)b * SS + s;
    u16 vh, vl;
    if (d < 128) { long long si = t * 4096 + hh * 256 + d; vh = kvbh[si]; vl = kvbl[si]; }
    else         { long long si = t * 64 + (d - 128);       vh = kpeh[si]; vl = kpel[si]; }
    long long di = ((long long)bh * SS + s) * 192 + d;
    krh[di] = vh; krl[di] = vl;
}

// =====================================================================
// vtprep: v^T planes [BH][128][S] from kvb planes (z selects plane)
// =====================================================================
__global__ __launch_bounds__(256) void vtprep_k(const u16* __restrict__ kvbh, const u16* __restrict__ kvbl,
                                                u16* vth, u16* vtl){
    __shared__ u16 L[64][136];
    int bh = blockIdx.x, st = blockIdx.y, pl = blockIdx.z;
    const u16* src = pl ? kvbl : kvbh;
    u16* dst = pl ? vtl : vth;
    int b = bh >> 4, hh = bh & 15;
    int tid = threadIdx.x;
#pragma unroll
    for (int it = 0; it < 4; ++it) {
        int idx = it * 256 + tid; int sl = idx >> 4, dc = idx & 15;
        long long t = (long long)b * SS + st * 64 + sl;
        *(short8*)&L[sl][dc * 8] = *(const short8*)(src + t * 4096 + hh * 256 + 128 + dc * 8);
    }
    __syncthreads();
#pragma unroll
    for (int it = 0; it < 4; ++it) {
        int idx = it * 256 + tid; int d = idx >> 3, sc = idx & 7;
        short8 v;
#pragma unroll
        for (int u = 0; u < 8; u++) v[u] = (short)L[sc * 8 + u][d];
        *(short8*)(dst + ((long long)bh * 128 + d) * SS + st * 64 + sc * 8) = v;
    }
}

// =====================================================================
// Flash attention, split-fp16, causal. 64 q-rows/block (4 waves x 16), 32-t tiles.
// =====================================================================
__global__ __launch_bounds__(256) void attn_k(
    const u16* __restrict__ qrh, const u16* __restrict__ qrl,
    const u16* __restrict__ krh, const u16* __restrict__ krl,
    const u16* __restrict__ vth, const u16* __restrict__ vtl,
    u16* ohi, u16* olo)
{
    __shared__ u16 KsH[32][200], KsL[32][200];
    __shared__ u16 VsH[128][40], VsL[128][40];
    __shared__ u16 PlH[4][16][40], PlL[4][16][40];
    int qi = blockIdx.x, bh = blockIdx.y;
    int b = bh >> 4, h = bh & 15;
    int tid = threadIdx.x, lane = tid & 63, wv = tid >> 6;
    int q0 = qi * 64;
    const u16* qbh = qrh + (long long)bh * SS * 192;
    const u16* qbl = qrl + (long long)bh * SS * 192;
    const u16* kbh = krh + (long long)bh * SS * 192;
    const u16* kbl = krl + (long long)bh * SS * 192;
    const u16* vbh = vth + (long long)bh * 128 * SS;
    const u16* vbl = vtl + (long long)bh * 128 * SS;

    half8 qh[6], ql[6];
    {
        int row = q0 + wv * 16 + (lane & 15);
        const u16* ph = qbh + (long long)row * 192 + (lane >> 4) * 8;
        const u16* pl = qbl + (long long)row * 192 + (lane >> 4) * 8;
#pragma unroll
        for (int ks = 0; ks < 6; ks++) {
            qh[ks] = *(const half8*)(ph + ks * 32);
            ql[ks] = *(const half8*)(pl + ks * 32);
        }
    }
    float mrun[4], lrun[4];
    f32x4 oacc[8];
#pragma unroll
    for (int r = 0; r < 4; r++) { mrun[r] = -1e30f; lrun[r] = 0.f; }
#pragma unroll
    for (int f = 0; f < 8; f++) { f32x4 z = {0.f,0.f,0.f,0.f}; oacc[f] = z; }
    const float scale = 0.07216878364870322f; // 1/sqrt(192)

    int ntile = 2 * qi + 2;
    for (int ti = 0; ti < ntile; ++ti) {
        int t0 = ti * 32;
        __syncthreads();
#pragma unroll
        for (int it = 0; it < 3; ++it) {
            int idx = it * 256 + tid; int r = idx / 24, c = idx % 24;
            *(short8*)&KsH[r][c * 8] = *(const short8*)(kbh + (long long)(t0 + r) * 192 + c * 8);
        }
#pragma unroll
        for (int it = 0; it < 3; ++it) {
            int idx = it * 256 + tid; int r = idx / 24, c = idx % 24;
            *(short8*)&KsL[r][c * 8] = *(const short8*)(kbl + (long long)(t0 + r) * 192 + c * 8);
        }
#pragma unroll
        for (int it = 0; it < 2; ++it) {
            int idx = it * 256 + tid; int r = idx >> 2, c = idx & 3;
            *(short8*)&VsH[r][c * 8] = *(const short8*)(vbh + (long long)r * SS + t0 + c * 8);
        }
#pragma unroll
        for (int it = 0; it < 2; ++it) {
            int idx = it * 256 + tid; int r = idx >> 2, c = idx & 3;
            *(short8*)&VsL[r][c * 8] = *(const short8*)(vbl + (long long)r * SS + t0 + c * 8);
        }
        __syncthreads();
        // scores: 2 n-tiles of 16 t-cols
        f32x4 s[2];
#pragma unroll
        for (int nt = 0; nt < 2; ++nt) {
            f32x4 a = {0.f,0.f,0.f,0.f};
#pragma unroll
            for (int ks = 0; ks < 6; ++ks) {
                half8 kh = *(const half8*)&KsH[nt * 16 + (lane & 15)][ks * 32 + (lane >> 4) * 8];
                half8 kl = *(const half8*)&KsL[nt * 16 + (lane & 15)][ks * 32 + (lane >> 4) * 8];
                a = __builtin_amdgcn_mfma_f32_16x16x32_f16(qh[ks], kh, a, 0, 0, 0);
                a = __builtin_amdgcn_mfma_f32_16x16x32_f16(qh[ks], kl, a, 0, 0, 0);
                a = __builtin_amdgcn_mfma_f32_16x16x32_f16(ql[ks], kh, a, 0, 0, 0);
            }
            s[nt] = a;
        }
        // scale + causal mask (only tiles crossing diag)
#pragma unroll
        for (int nt = 0; nt < 2; ++nt)
#pragma unroll
            for (int r = 0; r < 4; ++r) {
                float v = s[nt][r] * scale;
                if (ti >= 2 * qi) {
                    int t = t0 + nt * 16 + (lane & 15);
                    int sq = q0 + wv * 16 + (lane >> 4) * 4 + r;
                    if (t > sq) v = -1e30f;
                }
                s[nt][r] = v;
            }
        // online softmax
        float corr[4];
#pragma unroll
        for (int r = 0; r < 4; ++r) {
            float m = fmaxf(s[0][r], s[1][r]);
#pragma unroll
            for (int d = 1; d < 16; d <<= 1) m = fmaxf(m, __shfl_xor(m, d, 64));
            float mn = fmaxf(mrun[r], m);
            corr[r] = __expf(mrun[r] - mn);
            mrun[r] = mn;
        }
        float rs[4] = {0.f, 0.f, 0.f, 0.f};
#pragma unroll
        for (int nt = 0; nt < 2; ++nt)
#pragma unroll
            for (int r = 0; r < 4; ++r) {
                float p = __expf(s[nt][r] - mrun[r]);
                s[nt][r] = p;
                rs[r] += p;
            }
#pragma unroll
        for (int r = 0; r < 4; ++r) {
            float tsum = rs[r];
#pragma unroll
            for (int d = 1; d < 16; d <<= 1) tsum += __shfl_xor(tsum, d, 64);
            lrun[r] = lrun[r] * corr[r] + tsum;
        }
#pragma unroll
        for (int f = 0; f < 8; f++)
#pragma unroll
            for (int r = 0; r < 4; r++) oacc[f][r] *= corr[r];
        // write P (split) to per-wave LDS
#pragma unroll
        for (int nt = 0; nt < 2; ++nt)
#pragma unroll
            for (int r = 0; r < 4; ++r) {
                float p = s[nt][r];
                _Float16 ph = (_Float16)p;
                PlH[wv][(lane >> 4) * 4 + r][nt * 16 + (lane & 15)] = h2b(ph);
                PlL[wv][(lane >> 4) * 4 + r][nt * 16 + (lane & 15)] = h2b((_Float16)(p - (float)ph));
            }
        __syncthreads();
        // PV
        half8 pfh = *(const half8*)&PlH[wv][lane & 15][(lane >> 4) * 8];
        half8 pfl = *(const half8*)&PlL[wv][lane & 15][(lane >> 4) * 8];
#pragma unroll
        for (int f = 0; f < 8; ++f) {
            half8 vh = *(const half8*)&VsH[f * 16 + (lane & 15)][(lane >> 4) * 8];
            half8 vl = *(const half8*)&VsL[f * 16 + (lane & 15)][(lane >> 4) * 8];
            oacc[f] = __builtin_amdgcn_mfma_f32_16x16x32_f16(pfh, vh, oacc[f], 0, 0, 0);
            oacc[f] = __builtin_amdgcn_mfma_f32_16x16x32_f16(pfh, vl, oacc[f], 0, 0, 0);
            oacc[f] = __builtin_amdgcn_mfma_f32_16x16x32_f16(pfl, vh, oacc[f], 0, 0, 0);
        }
    }
    // epilogue: o/l -> fp16 pair at [b*S+sq][h*128 + d]
#pragma unroll
    for (int f = 0; f < 8; ++f)
#pragma unroll
        for (int r = 0; r < 4; ++r) {
            int sq = q0 + wv * 16 + (lane >> 4) * 4 + r;
            float v = oacc[f][r] / lrun[r];
            _Float16 hh = (_Float16)v;
            long long o = ((long long)(b * SS + sq)) * 2048 + h * 128 + f * 16 + (lane & 15);
            ohi[o] = h2b(hh);
            olo[o] = h2b((_Float16)(v - (float)hh));
        }
}

// =====================================================================
// gate: per-token f32 rmsnorm + 12 dots + sigmoid + top-4 (wave per token)
// =====================================================================
__global__ __launch_bounds__(256) void gate_k(const float* __restrict__ first,
    const float* __restrict__ nw, const float* __restrict__ gw, const float* __restrict__ gb,
    int* topi, float* wgt, int* cnt){
    int wv = threadIdx.x >> 6, lane = threadIdx.x & 63;
    int t = blockIdx.x * 4 + wv;
    const float* row = first + (long long)t * DD;
    float ss = 0.f;
    for (int i = lane; i < DD; i += 64) { float v = row[i]; ss += v * v; }
#pragma unroll
    for (int d = 1; d < 64; d <<= 1) ss += __shfl_xor(ss, d, 64);
    float sc = rsqrtf(ss / (float)DD + 1e-6f);
    float s[12];
#pragma unroll
    for (int e = 0; e < 12; e++) {
        float a = 0.f;
        for (int i = lane; i < DD; i += 64) a += row[i] * sc * nw[i] * gw[(long long)i * 12 + e];
#pragma unroll
        for (int d = 1; d < 64; d <<= 1) a += __shfl_xor(a, d, 64);
        s[e] = 1.f / (1.f + expf(-a));
    }
    if (lane == 0) {
        float rank[12];
#pragma unroll
        for (int e = 0; e < 12; e++) rank[e] = s[e] + gb[e];
        int sel[4]; float wv4[4]; float wsum = 0.f;
#pragma unroll
        for (int k = 0; k < 4; k++) {
            int bi = 0; float bv = -1e30f;
#pragma unroll
            for (int e = 0; e < 12; e++) if (rank[e] > bv) { bv = rank[e]; bi = e; }
            sel[k] = bi; rank[bi] = -1e31f;
            wv4[k] = s[bi]; wsum += s[bi];
        }
#pragma unroll
        for (int k = 0; k < 4; k++) {
            topi[t * 4 + k] = sel[k];
            wgt[t * 4 + k] = wv4[k] / wsum;
        }
#pragma unroll
        for (int k = 0; k < 4; k++) atomicAdd(&cnt[sel[k]], 1);
    }
}

__global__ void offs_k(const int* cnt, int* offs, int* cur){
    if (threadIdx.x == 0 && blockIdx.x == 0) {
        int a = 0;
        for (int e = 0; e < 12; e++) { offs[e] = a; a += cnt[e]; cur[e] = 0; }
        offs[12] = a;
    }
}

__global__ void scatter_k(const int* topi, const float* wgt, const int* offs,
    int* cur, int* tok, float* wgl, int* posm){
    int t = blockIdx.x * 256 + threadIdx.x;
    if (t >= TT) return;
    for (int k = 0; k < 4; k++) {
        int e = topi[t * 4 + k];
        int p = atomicAdd(&cur[e], 1);
        int pos = offs[e] + p;
        tok[pos] = t;
        wgl[pos] = wgt[t * 4 + k];
        posm[t * 4 + k] = pos;
    }
}

// =====================================================================
// final: out = first + shared + sum_k wgl*EO   (deterministic gather)
// =====================================================================
__global__ void final_k(const float* __restrict__ first, const float* __restrict__ so,
    const u16* __restrict__ eo, const int* __restrict__ posm, const float* __restrict__ wgl,
    float* out){
    int idx = blockIdx.x * 256 + threadIdx.x; // t*512 + d4
    int d4 = idx & 511, t = idx >> 9;
    int d = d4 * 4;
    const float* fp = first + (long long)t * DD + d;
    const float* sp = so + (long long)t * DD + d;
    float r0 = fp[0] + sp[0], r1 = fp[1] + sp[1], r2 = fp[2] + sp[2], r3 = fp[3] + sp[3];
#pragma unroll
    for (int k = 0; k < 4; k++) {
        int pos = posm[t * 4 + k];
        float wv = wgl[pos];
        const u16* ep = eo + (long long)pos * DD + d;
        r0 += wv * bf16_to_f32(ep[0]);
        r1 += wv * bf16_to_f32(ep[1]);
        r2 += wv * bf16_to_f32(ep[2]);
        r3 += wv * bf16_to_f32(ep[3]);
    }
    float4 res = {r0, r1, r2, r3};
    *(float4*)(out + (long long)t * DD + d) = res;
}

// =====================================================================
// host launch
// =====================================================================
extern "C" void kernel_launch(void* const* d_in, const int* in_sizes, int n_in,
                              void* d_out, int out_size, void* d_ws, size_t ws_size,
                              hipStream_t stream)
{
    const float* x       = (const float*)d_in[0];
    const float* wq      = (const float*)d_in[1];
    const float* wkv_a   = (const float*)d_in[2];
    const float* kvnw    = (const float*)d_in[3];
    const float* wkv_b   = (const float*)d_in[4];
    const float* wo      = (const float*)d_in[5];
    const float* norm_w  = (const float*)d_in[6];
    const float* gate_w  = (const float*)d_in[7];
    const float* gate_b  = (const float*)d_in[8];
    const float* w1      = (const float*)d_in[9];
    const float* w2      = (const float*)d_in[10];
    const float* w3      = (const float*)d_in[11];
    const float* ws1     = (const float*)d_in[12];
    const float* ws2     = (const float*)d_in[13];
    const float* ws3     = (const float*)d_in[14];
    const int*   startp  = (const int*)d_in[16];
    char* ws = (char*)d_ws;

    // ---------- workspace arena (total 144,179,200 bytes) ----------
    const size_t O_COS = 0, O_SIN = 131072, O_KPEH = 262144, O_KPEL = 524288;
    const size_t O_TOPI = 786432, O_WGT = 819200, O_TOK = 851968, O_WGL = 884736, O_POSM = 917504;
    const size_t O_CNT = 950272, O_OFFS = 950336, O_CUR = 950400;
    const size_t R1 = 1048576;
    const size_t O_HHI = R1, O_HLO = R1 + 8388608, O_KVF = R1 + 16777216,
                 O_LATH = R1 + 21495808, O_LATL = R1 + 23592960;
    const size_t R2 = 26738688;
    const size_t O_QHI = R2, O_QLO = R2 + 12582912, O_H1 = R2;
    const size_t R3 = 51904512;
    const size_t O_KVBH = R3, O_KVBL = R3 + 16777216, O_OHI = R3, O_OLO = R3 + 8388608, O_EO = R3;
    const size_t R4 = 85458944;
    const size_t O_KRH = R4, O_KRL = R4 + 12582912, O_SH1 = R4;
    const size_t R5 = 110624768;
    const size_t O_VTH = R5, O_VTL = R5 + 8388608;
    const size_t R6 = 127401984;
    const size_t O_FIRST = R6;
    const size_t O_QRH = R1, O_QRL = R1 + 12582912;  // overlays h/kv/lat (dead)
    const size_t O_TBF = R1, O_SO = R1 + 8388608;    // overlays q_r (dead)

    float* cosT = (float*)(ws + O_COS);  float* sinT = (float*)(ws + O_SIN);
    u16* kpeh = (u16*)(ws + O_KPEH);     u16* kpel = (u16*)(ws + O_KPEL);
    int* topi = (int*)(ws + O_TOPI);     float* wgt = (float*)(ws + O_WGT);
    int* tok = (int*)(ws + O_TOK);       float* wgl = (float*)(ws + O_WGL);
    int* posm = (int*)(ws + O_POSM);
    int* cntp = (int*)(ws + O_CNT); int* offsp = (int*)(ws + O_OFFS); int* curp = (int*)(ws + O_CUR);
    u16* hhi = (u16*)(ws + O_HHI);  u16* hlo = (u16*)(ws + O_HLO);
    float* kvf = (float*)(ws + O_KVF);
    u16* lath = (u16*)(ws + O_LATH); u16* latl = (u16*)(ws + O_LATL);
    u16* qhi = (u16*)(ws + O_QHI);  u16* qlo = (u16*)(ws + O_QLO);
    u16* kvbh = (u16*)(ws + O_KVBH); u16* kvbl = (u16*)(ws + O_KVBL);
    u16* qrh = (u16*)(ws + O_QRH);  u16* qrl = (u16*)(ws + O_QRL);
    u16* krh = (u16*)(ws + O_KRH);  u16* krl = (u16*)(ws + O_KRL);
    u16* vth = (u16*)(ws + O_VTH);  u16* vtl = (u16*)(ws + O_VTL);
    u16* oh  = (u16*)(ws + O_OHI);  u16* ol  = (u16*)(ws + O_OLO);
    float* first = (float*)(ws + O_FIRST);
    u16* tbf = (u16*)(ws + O_TBF);  float* sobuf = (float*)(ws + O_SO);
    u16* h1buf = (u16*)(ws + O_H1); u16* eo = (u16*)(ws + O_EO);
    u16* sh1 = (u16*)(ws + O_SH1);

    hipMemsetAsync(ws + O_CNT, 0, 64, stream);

    costab_k<<<128, 256, 0, stream>>>(startp, cosT, sinT);
    rms_k<0><<<TT, 256, 0, stream>>>(x, norm_w, hhi, hlo);
    // q = h @ wq  (precise)
    gemm_k<EPI_F16PAIR, true><<<dim3(24, 16, 1), 256, 0, stream>>>(
        hhi, hlo, 2048, wq, 3072, 0, 2048, 3072, 2048,
        nullptr, nullptr, nullptr, qhi, qlo, 3072, nullptr);
    // kv = h @ wkv_a  (precise, f32 out)
    gemm_k<EPI_F32, true><<<dim3(5, 16, 1), 256, 0, stream>>>(
        hhi, hlo, 2048, wkv_a, 576, 0, 2048, 576, 2048,
        nullptr, nullptr, nullptr, kvf, nullptr, 576, nullptr);
    kvprep_k<<<TT, 256, 0, stream>>>(kvf, kvnw, cosT, sinT, lath, latl, kpeh, kpel);
    // kvb = kv_lat @ wkv_b  (precise)
    gemm_k<EPI_F16PAIR, true><<<dim3(32, 16, 1), 256, 0, stream>>>(
        lath, latl, 512, wkv_b, 4096, 0, 2048, 4096, 512,
        nullptr, nullptr, nullptr, kvbh, kvbl, 4096, nullptr);
    qprep_k<<<12288, 256, 0, stream>>>(qhi, qlo, cosT, sinT, qrh, qrl);
    kprep_k<<<24576, 256, 0, stream>>>(kvbh, kvbl, kpeh, kpel, krh, krl);
    vtprep_k<<<dim3(32, 16, 2), 256, 0, stream>>>(kvbh, kvbl, vth, vtl);
    attn_k<<<dim3(16, 32, 1), 256, 0, stream>>>(qrh, qrl, krh, krl, vth, vtl, oh, ol);
    // first = o @ wo + x  (precise)
    gemm_k<EPI_RES, true><<<dim3(16, 16, 1), 256, 0, stream>>>(
        oh, ol, 2048, wo, 2048, 0, 2048, 2048, 2048,
        nullptr, nullptr, nullptr, first, nullptr, 2048, x);
    rms_k<1><<<TT, 256, 0, stream>>>(first, norm_w, tbf, nullptr);
    gate_k<<<512, 256, 0, stream>>>(first, norm_w, gate_w, gate_b, topi, wgt, cntp);
    offs_k<<<1, 64, 0, stream>>>(cntp, offsp, curp);
    scatter_k<<<8, 256, 0, stream>>>(topi, wgt, offsp, curp, tok, wgl, posm);
    // experts: H1 = gather(t) @ w1[e]
    gemm_k<EPI_BF16, false><<<dim3(11, 16, 12), 256, 0, stream>>>(
        tbf, nullptr, 2048, w1, 1408, (long long)2048 * 1408, 2048, 1408, 2048,
        offsp, cntp, tok, h1buf, nullptr, 1408, nullptr);
    // G = silu(H1) * (gather(t) @ w3[e])   (in place)
    gemm_k<EPI_SILUMUL, false><<<dim3(11, 16, 12), 256, 0, stream>>>(
        tbf, nullptr, 2048, w3, 1408, (long long)2048 * 1408, 2048, 1408, 2048,
        offsp, cntp, tok, h1buf, nullptr, 1408, h1buf);
    // EO = G @ w2[e]
    gemm_k<EPI_BF16, false><<<dim3(16, 16, 12), 256, 0, stream>>>(
        h1buf, nullptr, 1408, w2, 2048, (long long)1408 * 2048, 2048, 2048, 1408,
        offsp, cntp, nullptr, eo, nullptr, 2048, nullptr);
    // shared expert
    gemm_k<EPI_BF16, false><<<dim3(22, 16, 1), 256, 0, stream>>>(
        tbf, nullptr, 2048, ws1, 2816, 0, 2048, 2816, 2048,
        nullptr, nullptr, nullptr, sh1, nullptr, 2816, nullptr);
    gemm_k<EPI_SILUMUL, false><<<dim3(22, 16, 1), 256, 0, stream>>>(
        tbf, nullptr, 2048, ws3, 2816, 0, 2048, 2816, 2048,
        nullptr, nullptr, nullptr, sh1, nullptr, 2816, sh1);
    gemm_k<EPI_F32, false><<<dim3(16, 16, 1), 256, 0, stream>>>(
        sh1, nullptr, 2816, ws2, 2048, 0, 2048, 2048, 2816,
        nullptr, nullptr, nullptr, sobuf, nullptr, 2048, nullptr);
    final_k<<<4096, 256, 0, stream>>>(first, sobuf, eo, posm, wgl, (float*)d_out);
}

// Round 2
// 1527.159 us; speedup vs baseline: 1.8542x; 1.8542x over previous
//
#include <hip/hip_runtime.h>
#include <math.h>

// ---------- types ----------
typedef unsigned short u16;
typedef __attribute__((ext_vector_type(8))) short short8;     // 8x16-bit raw (bf16 bits)
typedef __attribute__((ext_vector_type(8))) _Float16 half8;   // 8x fp16
typedef __attribute__((ext_vector_type(4))) float f32x4;

__device__ inline u16 f32_to_bf16_rne(float f){
    unsigned int u = __float_as_uint(f);
    unsigned int r = (u + 0x7FFFu + ((u >> 16) & 1u)) >> 16;
    return (u16)r;
}
__device__ inline float bf16_to_f32(u16 h){ return __uint_as_float(((unsigned int)h) << 16); }
__device__ inline u16 h2b(_Float16 h){ union { _Float16 f; u16 u; } x; x.f = h; return x.u; }

// ---------- constants ----------
#define TT 2048      // tokens
#define DD 2048      // model dim
#define SS 1024      // seq len
#define NH 16        // heads

#define EPI_F32     0
#define EPI_BF16    1
#define EPI_RES     2
#define EPI_SILUMUL 3
#define EPI_F16PAIR 4
#define EPI_QROPE   5

// =====================================================================
// Transpose-convert: W[K][N] f32 -> WT[N][K] 16-bit planes.
// PAIR=1: fp16 hi/lo planes; PAIR=0: bf16 single plane.
// grid: (N/64, K/64, E)
// =====================================================================
template<int PAIR>
__global__ __launch_bounds__(256) void cvtT_k(const float* __restrict__ W, long long wstr,
        u16* __restrict__ WTh, u16* __restrict__ WTl, long long tstr, int K, int N){
    __shared__ float L[64][65];
    int e = blockIdx.z;
    const float* Wp = W + (long long)e * wstr;
    int k0 = blockIdx.y * 64, n0 = blockIdx.x * 64;
    int tid = threadIdx.x;
#pragma unroll
    for (int it = 0; it < 4; ++it) {
        int r = (tid >> 4) + it * 16, cc = (tid & 15) * 4;
        float4 v = *(const float4*)(Wp + (long long)(k0 + r) * N + n0 + cc);
        L[r][cc] = v.x; L[r][cc+1] = v.y; L[r][cc+2] = v.z; L[r][cc+3] = v.w;
    }
    __syncthreads();
#pragma unroll
    for (int it = 0; it < 2; ++it) {
        int idx = it * 256 + tid; int n = idx >> 3, kc = (idx & 7) * 8;
        u16 hi[8], lo[8];
#pragma unroll
        for (int u = 0; u < 8; ++u) {
            float v = L[kc + u][n];
            if (PAIR) { _Float16 h = (_Float16)v; hi[u] = h2b(h); lo[u] = h2b((_Float16)(v - (float)h)); }
            else hi[u] = f32_to_bf16_rne(v);
        }
        long long o = (long long)e * tstr + (long long)(n0 + n) * K + k0 + kc;
        *(short8*)(WTh + o) = *(short8*)hi;
        if (PAIR) *(short8*)(WTl + o) = *(short8*)lo;
    }
}

// =====================================================================
// 128x128 MFMA GEMM, pre-transposed 16-bit B (BT[N][K] planes).
// A: 16-bit planes [M][K] (fp16 hi/lo pair when PREC, else bf16).
// Expert grouping: e = ebase+blockIdx.z (offs/cnt), BT plane index blockIdx.z.
// =====================================================================
template<int EPI, bool PREC>
__global__ __launch_bounds__(256) void gemm_k(
    const u16* __restrict__ A0, const u16* __restrict__ A1, int lda,
    const u16* __restrict__ BTh, const u16* __restrict__ BTl, long long btstr,
    int M, int N, int K,
    const int* offs, const int* cnt, const int* gather, int ebase,
    void* C0, void* C1, int ldc,
    const void* aux, const float* __restrict__ cosT, const float* __restrict__ sinT)
{
    __shared__ u16 AsH[128][40];
    __shared__ u16 AsL[PREC ? 128 : 1][PREC ? 40 : 1];
    __shared__ u16 BsH[128][40];
    __shared__ u16 BsL[PREC ? 128 : 1][PREC ? 40 : 1];

    int tid  = threadIdx.x;
    int lane = tid & 63;
    int wv   = tid >> 6;
    int wm = (wv >> 1) * 64, wn = (wv & 1) * 64;

    int e    = ebase + blockIdx.z;
    int base = offs ? offs[e] : 0;
    int mc   = cnt ? cnt[e] : M;
    int m0   = blockIdx.y * 128;
    if (m0 >= mc) return;
    int n0 = blockIdx.x * 128;
    const u16* Bh = BTh + (long long)blockIdx.z * btstr;
    const u16* Bl = PREC ? (BTl + (long long)blockIdx.z * btstr) : (const u16*)nullptr;

    int r0 = tid >> 2, r1 = r0 + 64, c0 = tid & 3;
    long long arow0 = -1, arow1 = -1;
    if (m0 + r0 < mc) arow0 = gather ? (long long)gather[base + m0 + r0] : (long long)(base + m0 + r0);
    if (m0 + r1 < mc) arow1 = gather ? (long long)gather[base + m0 + r1] : (long long)(base + m0 + r1);
    bool bok0 = (n0 + r0) < N, bok1 = (n0 + r1) < N;

    f32x4 acc[4][4];
#pragma unroll
    for (int i = 0; i < 4; i++)
#pragma unroll
        for (int j = 0; j < 4; j++) { f32x4 z = {0.f,0.f,0.f,0.f}; acc[i][j] = z; }

    short8 zer = {0,0,0,0,0,0,0,0};
    short8 a0h, a1h, a0l, a1l, b0h, b1h, b0l, b1l;

#define GLOADS(KT)                                                                   \
    {                                                                                \
        a0h = (arow0 >= 0) ? *(const short8*)(A0 + arow0 * lda + (KT) + c0 * 8) : zer; \
        a1h = (arow1 >= 0) ? *(const short8*)(A0 + arow1 * lda + (KT) + c0 * 8) : zer; \
        b0h = bok0 ? *(const short8*)(Bh + (long long)(n0 + r0) * K + (KT) + c0 * 8) : zer; \
        b1h = bok1 ? *(const short8*)(Bh + (long long)(n0 + r1) * K + (KT) + c0 * 8) : zer; \
        if (PREC) {                                                                  \
            a0l = (arow0 >= 0) ? *(const short8*)(A1 + arow0 * lda + (KT) + c0 * 8) : zer; \
            a1l = (arow1 >= 0) ? *(const short8*)(A1 + arow1 * lda + (KT) + c0 * 8) : zer; \
            b0l = bok0 ? *(const short8*)(Bl + (long long)(n0 + r0) * K + (KT) + c0 * 8) : zer; \
            b1l = bok1 ? *(const short8*)(Bl + (long long)(n0 + r1) * K + (KT) + c0 * 8) : zer; \
        }                                                                            \
    }

    GLOADS(0);
    for (int kt = 0; kt < K; kt += 32) {
        __syncthreads();
        *(short8*)&AsH[r0][c0 * 8] = a0h;
        *(short8*)&AsH[r1][c0 * 8] = a1h;
        *(short8*)&BsH[r0][c0 * 8] = b0h;
        *(short8*)&BsH[r1][c0 * 8] = b1h;
        if (PREC) {
            *(short8*)&AsL[r0][c0 * 8] = a0l;
            *(short8*)&AsL[r1][c0 * 8] = a1l;
            *(short8*)&BsL[r0][c0 * 8] = b0l;
            *(short8*)&BsL[r1][c0 * 8] = b1l;
        }
        __syncthreads();
        if (kt + 32 < K) GLOADS(kt + 32);
        if (PREC) {
            half8 ah[4], al[4];
#pragma unroll
            for (int i = 0; i < 4; i++) {
                ah[i] = *(const half8*)&AsH[wm + i * 16 + (lane & 15)][(lane >> 4) * 8];
                al[i] = *(const half8*)&AsL[wm + i * 16 + (lane & 15)][(lane >> 4) * 8];
            }
#pragma unroll
            for (int j = 0; j < 4; j++) {
                int rb = wn + j * 16 + (lane & 15);
                half8 bh = *(const half8*)&BsH[rb][(lane >> 4) * 8];
                half8 bl = *(const half8*)&BsL[rb][(lane >> 4) * 8];
#pragma unroll
                for (int i = 0; i < 4; i++) {
                    acc[i][j] = __builtin_amdgcn_mfma_f32_16x16x32_f16(ah[i], bh, acc[i][j], 0, 0, 0);
                    acc[i][j] = __builtin_amdgcn_mfma_f32_16x16x32_f16(ah[i], bl, acc[i][j], 0, 0, 0);
                    acc[i][j] = __builtin_amdgcn_mfma_f32_16x16x32_f16(al[i], bh, acc[i][j], 0, 0, 0);
                }
            }
        } else {
            short8 af[4];
#pragma unroll
            for (int i = 0; i < 4; i++)
                af[i] = *(const short8*)&AsH[wm + i * 16 + (lane & 15)][(lane >> 4) * 8];
#pragma unroll
            for (int j = 0; j < 4; j++) {
                int rb = wn + j * 16 + (lane & 15);
                short8 bfr = *(const short8*)&BsH[rb][(lane >> 4) * 8];
#pragma unroll
                for (int i = 0; i < 4; i++)
                    acc[i][j] = __builtin_amdgcn_mfma_f32_16x16x32_bf16(af[i], bfr, acc[i][j], 0, 0, 0);
            }
        }
    }
#undef GLOADS

    // ---- epilogue ----
    if (EPI == EPI_QROPE) {
        // exact dims (M=2048, N=3072): no guards; RoPE pairs via lane xor
#pragma unroll
        for (int i = 0; i < 4; i++) {
            int rr0 = m0 + wm + i * 16 + ((lane >> 4) << 2);
#pragma unroll
            for (int j = 0; j < 4; j++) {
                int col = n0 + wn + j * 16 + (lane & 15);
                int hd = col % 192;
#pragma unroll
                for (int r = 0; r < 4; r++) {
                    int rr = rr0 + r;
                    float v = acc[i][j][r];
                    float pv = __shfl_xor(v, 1);
                    float outv = v;
                    if (hd >= 128) {
                        int s = rr & (SS - 1);
                        int pi2 = (hd - 128) >> 1;
                        float cc_ = cosT[s * 32 + pi2], sn_ = sinT[s * 32 + pi2];
                        bool odd = col & 1;
                        float a0 = odd ? pv : v, a1 = odd ? v : pv;
                        outv = odd ? (a0 * sn_ + a1 * cc_) : (a0 * cc_ - a1 * sn_);
                    }
                    long long cidx = (long long)rr * ldc + col;
                    _Float16 hh = (_Float16)outv;
                    ((u16*)C0)[cidx] = h2b(hh);
                    ((u16*)C1)[cidx] = h2b((_Float16)(outv - (float)hh));
                }
            }
        }
    } else {
#pragma unroll
        for (int i = 0; i < 4; i++) {
            int rbase = m0 + wm + i * 16 + ((lane >> 4) << 2);
#pragma unroll
            for (int j = 0; j < 4; j++) {
                int col = n0 + wn + j * 16 + (lane & 15);
                if (col >= N) continue;
#pragma unroll
                for (int r = 0; r < 4; r++) {
                    int rr = rbase + r;
                    if (rr >= mc) continue;
                    long long cidx = (long long)(base + rr) * ldc + col;
                    float v = acc[i][j][r];
                    if (EPI == EPI_F32)      ((float*)C0)[cidx] = v;
                    else if (EPI == EPI_BF16) ((u16*)C0)[cidx] = f32_to_bf16_rne(v);
                    else if (EPI == EPI_RES)  ((float*)C0)[cidx] = v + ((const float*)aux)[cidx];
                    else if (EPI == EPI_SILUMUL) {
                        float h1v = bf16_to_f32(((const u16*)aux)[cidx]);
                        float g = h1v / (1.f + __expf(-h1v)) * v;
                        ((u16*)C0)[cidx] = f32_to_bf16_rne(g);
                    } else { // F16PAIR
                        _Float16 hh = (_Float16)v;
                        ((u16*)C0)[cidx] = h2b(hh);
                        ((u16*)C1)[cidx] = h2b((_Float16)(v - (float)hh));
                    }
                }
            }
        }
    }
}

// =====================================================================
// cos/sin table: [S][32]
// =====================================================================
__global__ void costab_k(const int* sp, float* ct, float* st){
    int idx = blockIdx.x * 256 + threadIdx.x;
    if (idx >= SS * 32) return;
    int i = idx & 31, s = idx >> 5;
    float inv = powf(10000.0f, -(float)i / 32.0f);
    float a = (float)(sp[0] + s) * inv;
    ct[idx] = cosf(a);
    st[idx] = sinf(a);
}

// =====================================================================
// rmsnorm: row of 2048 f32 -> MODE 0: fp16 hi/lo planes; MODE 1: bf16
// =====================================================================
template<int MODE>
__global__ __launch_bounds__(256) void rms_k(const float* __restrict__ x, const float* __restrict__ w,
                                             u16* o0, u16* o1){
    int t = blockIdx.x, tid = threadIdx.x;
    const float* row = x + (long long)t * DD;
    float4 v0 = *(const float4*)(row + tid * 4);
    float4 v1 = *(const float4*)(row + 1024 + tid * 4);
    float ss = v0.x*v0.x + v0.y*v0.y + v0.z*v0.z + v0.w*v0.w
             + v1.x*v1.x + v1.y*v1.y + v1.z*v1.z + v1.w*v1.w;
#pragma unroll
    for (int d = 1; d < 64; d <<= 1) ss += __shfl_xor(ss, d, 64);
    __shared__ float red[4];
    if ((tid & 63) == 0) red[tid >> 6] = ss;
    __syncthreads();
    float sc = rsqrtf((red[0] + red[1] + red[2] + red[3]) / (float)DD + 1e-6f);
    float a[8];
    a[0]=v0.x; a[1]=v0.y; a[2]=v0.z; a[3]=v0.w; a[4]=v1.x; a[5]=v1.y; a[6]=v1.z; a[7]=v1.w;
#pragma unroll
    for (int q2 = 0; q2 < 8; q2++) {
        int d = (q2 < 4) ? (tid * 4 + q2) : (1024 + tid * 4 + (q2 - 4));
        float y = a[q2] * sc * w[d];
        if (MODE == 0) {
            _Float16 hh = (_Float16)y;
            o0[(long long)t * DD + d] = h2b(hh);
            o1[(long long)t * DD + d] = h2b((_Float16)(y - (float)hh));
        } else {
            o0[(long long)t * DD + d] = f32_to_bf16_rne(y);
        }
    }
}

// =====================================================================
// kvprep: rmsnorm(kv[:,:512]) -> fp16 pair; rope(kv[:,512:576]) -> fp16 pair
// =====================================================================
__global__ __launch_bounds__(256) void kvprep_k(const float* __restrict__ kv, const float* __restrict__ kw,
    const float* __restrict__ ct, const float* __restrict__ st,
    u16* lath, u16* latl, u16* kpeh, u16* kpel){
    int t = blockIdx.x, tid = threadIdx.x;
    const float* row = kv + (long long)t * 576;
    float x0 = row[tid], x1 = row[256 + tid];
    float ss = x0 * x0 + x1 * x1;
#pragma unroll
    for (int d = 1; d < 64; d <<= 1) ss += __shfl_xor(ss, d, 64);
    __shared__ float red[4];
    if ((tid & 63) == 0) red[tid >> 6] = ss;
    __syncthreads();
    float sc = rsqrtf((red[0] + red[1] + red[2] + red[3]) / 512.f + 1e-6f);
    float y0 = x0 * sc * kw[tid], y1 = x1 * sc * kw[256 + tid];
    _Float16 h0 = (_Float16)y0, h1 = (_Float16)y1;
    lath[(long long)t * 512 + tid] = h2b(h0);
    latl[(long long)t * 512 + tid] = h2b((_Float16)(y0 - (float)h0));
    lath[(long long)t * 512 + 256 + tid] = h2b(h1);
    latl[(long long)t * 512 + 256 + tid] = h2b((_Float16)(y1 - (float)h1));
    if (tid < 32) {
        int s = t & (SS - 1);
        float a0 = row[512 + 2 * tid], a1 = row[513 + 2 * tid];
        float c = ct[s * 32 + tid], sn = st[s * 32 + tid];
        float r0 = a0 * c - a1 * sn, r1 = a0 * sn + a1 * c;
        _Float16 p0 = (_Float16)r0, p1 = (_Float16)r1;
        kpeh[(long long)t * 64 + 2 * tid]     = h2b(p0);
        kpel[(long long)t * 64 + 2 * tid]     = h2b((_Float16)(r0 - (float)p0));
        kpeh[(long long)t * 64 + 2 * tid + 1] = h2b(p1);
        kpel[(long long)t * 64 + 2 * tid + 1] = h2b((_Float16)(r1 - (float)p1));
    }
}

// =====================================================================
// vtprep: v^T planes [BH][128][S] from kvb planes (z selects plane)
// =====================================================================
__global__ __launch_bounds__(256) void vtprep_k(const u16* __restrict__ kvbh, const u16* __restrict__ kvbl,
                                                u16* vth, u16* vtl){
    __shared__ u16 L[64][136];
    int bh = blockIdx.x, st = blockIdx.y, pl = blockIdx.z;
    const u16* src = pl ? kvbl : kvbh;
    u16* dst = pl ? vtl : vth;
    int b = bh >> 4, hh = bh & 15;
    int tid = threadIdx.x;
#pragma unroll
    for (int it = 0; it < 4; ++it) {
        int idx = it * 256 + tid; int sl = idx >> 4, dc = idx & 15;
        long long t = (long long)b * SS + st * 64 + sl;
        *(short8*)&L[sl][dc * 8] = *(const short8*)(src + t * 4096 + hh * 256 + 128 + dc * 8);
    }
    __syncthreads();
#pragma unroll
    for (int it = 0; it < 4; ++it) {
        int idx = it * 256 + tid; int d = idx >> 3, sc = idx & 7;
        short8 v;
#pragma unroll
        for (int u = 0; u < 8; u++) v[u] = (short)L[sc * 8 + u][d];
        *(short8*)(dst + ((long long)bh * 128 + d) * SS + st * 64 + sc * 8) = v;
    }
}

// =====================================================================
// Flash attention, split-fp16, causal. Q from q planes [T][3072] (roped),
// K staged from kvb planes (nope) + kpe planes (pe), V from vt planes.
// =====================================================================
__global__ __launch_bounds__(256) void attn_k(
    const u16* __restrict__ qh_, const u16* __restrict__ ql_,
    const u16* __restrict__ kvbh, const u16* __restrict__ kvbl,
    const u16* __restrict__ kpeh, const u16* __restrict__ kpel,
    const u16* __restrict__ vth, const u16* __restrict__ vtl,
    u16* ohi, u16* olo)
{
    __shared__ u16 KsH[32][200], KsL[32][200];
    __shared__ u16 VsH[128][40], VsL[128][40];
    __shared__ u16 PlH[4][16][40], PlL[4][16][40];
    int qi = blockIdx.x, bh = blockIdx.y;
    int b = bh >> 4, h = bh & 15;
    int tid = threadIdx.x, lane = tid & 63, wv = tid >> 6;
    int q0 = qi * 64;
    const u16* vbh = vth + (long long)bh * 128 * SS;
    const u16* vbl = vtl + (long long)bh * 128 * SS;

    half8 qh[6], ql[6];
    {
        int row = q0 + wv * 16 + (lane & 15);
        const u16* ph = qh_ + (long long)(b * SS + row) * 3072 + h * 192 + (lane >> 4) * 8;
        const u16* pl = ql_ + (long long)(b * SS + row) * 3072 + h * 192 + (lane >> 4) * 8;
#pragma unroll
        for (int ks = 0; ks < 6; ks++) {
            qh[ks] = *(const half8*)(ph + ks * 32);
            ql[ks] = *(const half8*)(pl + ks * 32);
        }
    }
    float mrun[4], lrun[4];
    f32x4 oacc[8];
#pragma unroll
    for (int r = 0; r < 4; r++) { mrun[r] = -1e30f; lrun[r] = 0.f; }
#pragma unroll
    for (int f = 0; f < 8; f++) { f32x4 z = {0.f,0.f,0.f,0.f}; oacc[f] = z; }
    const float scale = 0.07216878364870322f; // 1/sqrt(192)

    int ntile = 2 * qi + 2;
    for (int ti = 0; ti < ntile; ++ti) {
        int t0 = ti * 32;
        __syncthreads();
#pragma unroll
        for (int it = 0; it < 3; ++it) {
            int idx = it * 256 + tid; int r = idx / 24, c = idx % 24;
            long long tg = (long long)b * SS + t0 + r;
            short8 vh, vl;
            if (c < 16) {
                vh = *(const short8*)(kvbh + tg * 4096 + h * 256 + c * 8);
                vl = *(const short8*)(kvbl + tg * 4096 + h * 256 + c * 8);
            } else {
                vh = *(const short8*)(kpeh + tg * 64 + (c - 16) * 8);
                vl = *(const short8*)(kpel + tg * 64 + (c - 16) * 8);
            }
            *(short8*)&KsH[r][c * 8] = vh;
            *(short8*)&KsL[r][c * 8] = vl;
        }
#pragma unroll
        for (int it = 0; it < 2; ++it) {
            int idx = it * 256 + tid; int r = idx >> 2, c = idx & 3;
            *(short8*)&VsH[r][c * 8] = *(const short8*)(vbh + (long long)r * SS + t0 + c * 8);
            *(short8*)&VsL[r][c * 8] = *(const short8*)(vbl + (long long)r * SS + t0 + c * 8);
        }
        __syncthreads();
        // scores: 2 n-tiles of 16 t-cols
        f32x4 s[2];
#pragma unroll
        for (int nt = 0; nt < 2; ++nt) {
            f32x4 a = {0.f,0.f,0.f,0.f};
#pragma unroll
            for (int ks = 0; ks < 6; ++ks) {
                half8 kh = *(const half8*)&KsH[nt * 16 + (lane & 15)][ks * 32 + (lane >> 4) * 8];
                half8 kl = *(const half8*)&KsL[nt * 16 + (lane & 15)][ks * 32 + (lane >> 4) * 8];
                a = __builtin_amdgcn_mfma_f32_16x16x32_f16(qh[ks], kh, a, 0, 0, 0);
                a = __builtin_amdgcn_mfma_f32_16x16x32_f16(qh[ks], kl, a, 0, 0, 0);
                a = __builtin_amdgcn_mfma_f32_16x16x32_f16(ql[ks], kh, a, 0, 0, 0);
            }
            s[nt] = a;
        }
#pragma unroll
        for (int nt = 0; nt < 2; ++nt)
#pragma unroll
            for (int r = 0; r < 4; ++r) {
                float v = s[nt][r] * scale;
                if (ti >= 2 * qi) {
                    int t = t0 + nt * 16 + (lane & 15);
                    int sq = q0 + wv * 16 + (lane >> 4) * 4 + r;
                    if (t > sq) v = -1e30f;
                }
                s[nt][r] = v;
            }
        float corr[4];
#pragma unroll
        for (int r = 0; r < 4; ++r) {
            float m = fmaxf(s[0][r], s[1][r]);
#pragma unroll
            for (int d = 1; d < 16; d <<= 1) m = fmaxf(m, __shfl_xor(m, d, 64));
            float mn = fmaxf(mrun[r], m);
            corr[r] = __expf(mrun[r] - mn);
            mrun[r] = mn;
        }
        float rs[4] = {0.f, 0.f, 0.f, 0.f};
#pragma unroll
        for (int nt = 0; nt < 2; ++nt)
#pragma unroll
            for (int r = 0; r < 4; ++r) {
                float p = __expf(s[nt][r] - mrun[r]);
                s[nt][r] = p;
                rs[r] += p;
            }
#pragma unroll
        for (int r = 0; r < 4; ++r) {
            float tsum = rs[r];
#pragma unroll
            for (int d = 1; d < 16; d <<= 1) tsum += __shfl_xor(tsum, d, 64);
            lrun[r] = lrun[r] * corr[r] + tsum;
        }
#pragma unroll
        for (int f = 0; f < 8; f++)
#pragma unroll
            for (int r = 0; r < 4; r++) oacc[f][r] *= corr[r];
#pragma unroll
        for (int nt = 0; nt < 2; ++nt)
#pragma unroll
            for (int r = 0; r < 4; ++r) {
                float p = s[nt][r];
                _Float16 ph = (_Float16)p;
                PlH[wv][(lane >> 4) * 4 + r][nt * 16 + (lane & 15)] = h2b(ph);
                PlL[wv][(lane >> 4) * 4 + r][nt * 16 + (lane & 15)] = h2b((_Float16)(p - (float)ph));
            }
        __syncthreads();
        half8 pfh = *(const half8*)&PlH[wv][lane & 15][(lane >> 4) * 8];
        half8 pfl = *(const half8*)&PlL[wv][lane & 15][(lane >> 4) * 8];
#pragma unroll
        for (int f = 0; f < 8; ++f) {
            half8 vh = *(const half8*)&VsH[f * 16 + (lane & 15)][(lane >> 4) * 8];
            half8 vl = *(const half8*)&VsL[f * 16 + (lane & 15)][(lane >> 4) * 8];
            oacc[f] = __builtin_amdgcn_mfma_f32_16x16x32_f16(pfh, vh, oacc[f], 0, 0, 0);
            oacc[f] = __builtin_amdgcn_mfma_f32_16x16x32_f16(pfh, vl, oacc[f], 0, 0, 0);
            oacc[f] = __builtin_amdgcn_mfma_f32_16x16x32_f16(pfl, vh, oacc[f], 0, 0, 0);
        }
    }
#pragma unroll
    for (int f = 0; f < 8; ++f)
#pragma unroll
        for (int r = 0; r < 4; ++r) {
            int sq = q0 + wv * 16 + (lane >> 4) * 4 + r;
            float v = oacc[f][r] / lrun[r];
            _Float16 hh = (_Float16)v;
            long long o = ((long long)(b * SS + sq)) * 2048 + h * 128 + f * 16 + (lane & 15);
            ohi[o] = h2b(hh);
            olo[o] = h2b((_Float16)(v - (float)hh));
        }
}

// =====================================================================
// gate: per-token f32 rmsnorm + 12 dots + sigmoid + top-4 (wave per token)
// =====================================================================
__global__ __launch_bounds__(256) void gate_k(const float* __restrict__ first,
    const float* __restrict__ nw, const float* __restrict__ gw, const float* __restrict__ gb,
    int* topi, float* wgt, int* cnt){
    int wv = threadIdx.x >> 6, lane = threadIdx.x & 63;
    int t = blockIdx.x * 4 + wv;
    const float* row = first + (long long)t * DD;
    float ss = 0.f;
    for (int i = lane; i < DD; i += 64) { float v = row[i]; ss += v * v; }
#pragma unroll
    for (int d = 1; d < 64; d <<= 1) ss += __shfl_xor(ss, d, 64);
    float sc = rsqrtf(ss / (float)DD + 1e-6f);
    float s[12];
#pragma unroll
    for (int e = 0; e < 12; e++) {
        float a = 0.f;
        for (int i = lane; i < DD; i += 64) a += row[i] * sc * nw[i] * gw[(long long)i * 12 + e];
#pragma unroll
        for (int d = 1; d < 64; d <<= 1) a += __shfl_xor(a, d, 64);
        s[e] = 1.f / (1.f + expf(-a));
    }
    if (lane == 0) {
        float rank[12];
#pragma unroll
        for (int e = 0; e < 12; e++) rank[e] = s[e] + gb[e];
        int sel[4]; float wv4[4]; float wsum = 0.f;
#pragma unroll
        for (int k = 0; k < 4; k++) {
            int bi = 0; float bv = -1e30f;
#pragma unroll
            for (int e = 0; e < 12; e++) if (rank[e] > bv) { bv = rank[e]; bi = e; }
            sel[k] = bi; rank[bi] = -1e31f;
            wv4[k] = s[bi]; wsum += s[bi];
        }
#pragma unroll
        for (int k = 0; k < 4; k++) {
            topi[t * 4 + k] = sel[k];
            wgt[t * 4 + k] = wv4[k] / wsum;
        }
#pragma unroll
        for (int k = 0; k < 4; k++) atomicAdd(&cnt[sel[k]], 1);
    }
}

__global__ void offs_k(const int* cnt, int* offs, int* cur){
    if (threadIdx.x == 0 && blockIdx.x == 0) {
        int a = 0;
        for (int e = 0; e < 12; e++) { offs[e] = a; a += cnt[e]; cur[e] = 0; }
        offs[12] = a;
    }
}

__global__ void scatter_k(const int* topi, const float* wgt, const int* offs,
    int* cur, int* tok, float* wgl, int* posm){
    int t = blockIdx.x * 256 + threadIdx.x;
    if (t >= TT) return;
    for (int k = 0; k < 4; k++) {
        int e = topi[t * 4 + k];
        int p = atomicAdd(&cur[e], 1);
        int pos = offs[e] + p;
        tok[pos] = t;
        wgl[pos] = wgt[t * 4 + k];
        posm[t * 4 + k] = pos;
    }
}

// =====================================================================
// final: out = first + shared(bf16) + sum_k wgl*EO   (deterministic gather)
// =====================================================================
__global__ void final_k(const float* __restrict__ first, const u16* __restrict__ so,
    const u16* __restrict__ eo, const int* __restrict__ posm, const float* __restrict__ wgl,
    float* out){
    int idx = blockIdx.x * 256 + threadIdx.x; // t*512 + d4
    int d4 = idx & 511, t = idx >> 9;
    int d = d4 * 4;
    const float* fp = first + (long long)t * DD + d;
    const u16* sp = so + (long long)t * DD + d;
    float r0 = fp[0] + bf16_to_f32(sp[0]);
    float r1 = fp[1] + bf16_to_f32(sp[1]);
    float r2 = fp[2] + bf16_to_f32(sp[2]);
    float r3 = fp[3] + bf16_to_f32(sp[3]);
#pragma unroll
    for (int k = 0; k < 4; k++) {
        int pos = posm[t * 4 + k];
        float wv = wgl[pos];
        const u16* ep = eo + (long long)pos * DD + d;
        r0 += wv * bf16_to_f32(ep[0]);
        r1 += wv * bf16_to_f32(ep[1]);
        r2 += wv * bf16_to_f32(ep[2]);
        r3 += wv * bf16_to_f32(ep[3]);
    }
    float4 res = {r0, r1, r2, r3};
    *(float4*)(out + (long long)t * DD + d) = res;
}

// =====================================================================
// host launch
// =====================================================================
extern "C" void kernel_launch(void* const* d_in, const int* in_sizes, int n_in,
                              void* d_out, int out_size, void* d_ws, size_t ws_size,
                              hipStream_t stream)
{
    const float* x       = (const float*)d_in[0];
    const float* wq      = (const float*)d_in[1];
    const float* wkv_a   = (const float*)d_in[2];
    const float* kvnw    = (const float*)d_in[3];
    const float* wkv_b   = (const float*)d_in[4];
    const float* wo      = (const float*)d_in[5];
    const float* norm_w  = (const float*)d_in[6];
    const float* gate_w  = (const float*)d_in[7];
    const float* gate_b  = (const float*)d_in[8];
    const float* w1      = (const float*)d_in[9];
    const float* w2      = (const float*)d_in[10];
    const float* w3      = (const float*)d_in[11];
    const float* ws1     = (const float*)d_in[12];
    const float* ws2     = (const float*)d_in[13];
    const float* ws3     = (const float*)d_in[14];
    const int*   startp  = (const int*)d_in[16];
    char* ws = (char*)d_ws;

    // ---------- workspace arena (peak 136,314,880 bytes) ----------
    const size_t O_COS = 0, O_SIN = 131072, O_KPEH = 262144, O_KPEL = 524288;
    const size_t O_TOPI = 786432, O_WGT = 819200, O_TOK = 851968, O_WGL = 884736, O_POSM = 917504;
    const size_t O_CNT = 950272, O_OFFS = 950336, O_CUR = 950400;
    const size_t O_WB = 1048576;           // weight staging, 25,165,824 bytes (reused)
    const size_t B2 = 26214400;
    const size_t O_H    = B2,             O_HLO  = B2 + 8388608;    // h planes (dead after kv_a)
    const size_t O_Q    = B2 + 16777216,  O_QLO  = B2 + 29360128;   // roped q planes (dead after attn)
    const size_t O_KVF  = B2 + 41943040;                            // kv f32 (dead after kvprep)
    const size_t O_LATH = B2 + 46661632,  O_LATL = B2 + 48758784;   // latent planes
    const size_t O_KVBH = B2 + 50855936,  O_KVBL = B2 + 67633152;   // kvb planes (dead after attn)
    const size_t O_VTH  = B2,             O_VTL  = B2 + 8388608;    // overlays h
    const size_t O_OH   = B2 + 84410368,  O_OL   = B2 + 92798976;   // attn out planes
    const size_t O_FIRST= B2 + 16777216;                            // overlays q
    const size_t O_TBF  = B2;                                       // overlays vt
    const size_t O_H1   = B2 + 33554432;                            // 23,068,672
    const size_t O_EO   = B2 + 56623104;                            // 33,554,432
    const size_t O_SH1  = B2 + 90177536;                            // 11,534,336
    const size_t O_SO   = B2 + 101711872;                           // bf16, 8,388,608

    float* cosT = (float*)(ws + O_COS);  float* sinT = (float*)(ws + O_SIN);
    u16* kpeh = (u16*)(ws + O_KPEH);     u16* kpel = (u16*)(ws + O_KPEL);
    int* topi = (int*)(ws + O_TOPI);     float* wgt = (float*)(ws + O_WGT);
    int* tok = (int*)(ws + O_TOK);       float* wgl = (float*)(ws + O_WGL);
    int* posm = (int*)(ws + O_POSM);
    int* cntp = (int*)(ws + O_CNT); int* offsp = (int*)(ws + O_OFFS); int* curp = (int*)(ws + O_CUR);
    u16* WB   = (u16*)(ws + O_WB);
    u16* hhi = (u16*)(ws + O_H);    u16* hlo = (u16*)(ws + O_HLO);
    u16* qhp = (u16*)(ws + O_Q);    u16* qlp = (u16*)(ws + O_QLO);
    float* kvf = (float*)(ws + O_KVF);
    u16* lath = (u16*)(ws + O_LATH); u16* latl = (u16*)(ws + O_LATL);
    u16* kvbh = (u16*)(ws + O_KVBH); u16* kvbl = (u16*)(ws + O_KVBL);
    u16* vth = (u16*)(ws + O_VTH);  u16* vtl = (u16*)(ws + O_VTL);
    u16* oh  = (u16*)(ws + O_OH);   u16* ol  = (u16*)(ws + O_OL);
    float* first = (float*)(ws + O_FIRST);
    u16* tbf = (u16*)(ws + O_TBF);
    u16* h1buf = (u16*)(ws + O_H1); u16* eo = (u16*)(ws + O_EO);
    u16* sh1 = (u16*)(ws + O_SH1);  u16* sobuf = (u16*)(ws + O_SO);

    hipMemsetAsync(ws + O_CNT, 0, 64, stream);
    costab_k<<<128, 256, 0, stream>>>(startp, cosT, sinT);
    rms_k<0><<<TT, 256, 0, stream>>>(x, norm_w, hhi, hlo);

    // ---- q = rope(h @ wq) ---- (precise)
    cvtT_k<1><<<dim3(48, 32, 1), 256, 0, stream>>>(wq, 0, WB, WB + 6291456, 0, 2048, 3072);
    gemm_k<EPI_QROPE, true><<<dim3(24, 16, 1), 256, 0, stream>>>(
        hhi, hlo, 2048, WB, WB + 6291456, 0, 2048, 3072, 2048,
        nullptr, nullptr, nullptr, 0, qhp, qlp, 3072, nullptr, cosT, sinT);

    // ---- kv = h @ wkv_a ---- (precise, f32 out)
    cvtT_k<1><<<dim3(9, 32, 1), 256, 0, stream>>>(wkv_a, 0, WB, WB + 1179648, 0, 2048, 576);
    gemm_k<EPI_F32, true><<<dim3(5, 16, 1), 256, 0, stream>>>(
        hhi, hlo, 2048, WB, WB + 1179648, 0, 2048, 576, 2048,
        nullptr, nullptr, nullptr, 0, kvf, nullptr, 576, nullptr, nullptr, nullptr);
    kvprep_k<<<TT, 256, 0, stream>>>(kvf, kvnw, cosT, sinT, lath, latl, kpeh, kpel);

    // ---- kvb = kv_lat @ wkv_b ---- (precise)
    cvtT_k<1><<<dim3(64, 8, 1), 256, 0, stream>>>(wkv_b, 0, WB, WB + 2097152, 0, 512, 4096);
    gemm_k<EPI_F16PAIR, true><<<dim3(32, 16, 1), 256, 0, stream>>>(
        lath, latl, 512, WB, WB + 2097152, 0, 2048, 4096, 512,
        nullptr, nullptr, nullptr, 0, kvbh, kvbl, 4096, nullptr, nullptr, nullptr);

    vtprep_k<<<dim3(32, 16, 2), 256, 0, stream>>>(kvbh, kvbl, vth, vtl);
    attn_k<<<dim3(16, 32, 1), 256, 0, stream>>>(qhp, qlp, kvbh, kvbl, kpeh, kpel, vth, vtl, oh, ol);

    // ---- first = o @ wo + x ---- (precise)
    cvtT_k<1><<<dim3(32, 32, 1), 256, 0, stream>>>(wo, 0, WB, WB + 4194304, 0, 2048, 2048);
    gemm_k<EPI_RES, true><<<dim3(16, 16, 1), 256, 0, stream>>>(
        oh, ol, 2048, WB, WB + 4194304, 0, 2048, 2048, 2048,
        nullptr, nullptr, nullptr, 0, first, nullptr, 2048, x, nullptr, nullptr);

    rms_k<1><<<TT, 256, 0, stream>>>(first, norm_w, tbf, nullptr);
    gate_k<<<512, 256, 0, stream>>>(first, norm_w, gate_w, gate_b, topi, wgt, cntp);
    offs_k<<<1, 64, 0, stream>>>(cntp, offsp, curp);
    scatter_k<<<8, 256, 0, stream>>>(topi, wgt, offsp, curp, tok, wgl, posm);

    // ---- routed experts, groups of 4 (weight staging reuses WB) ----
    const long long EW = (long long)2048 * 1408;   // elements per expert weight
    for (int g = 0; g < 3; ++g) {
        cvtT_k<0><<<dim3(22, 32, 4), 256, 0, stream>>>(w1 + (long long)g * 4 * EW, EW, WB, nullptr, EW, 2048, 1408);
        gemm_k<EPI_BF16, false><<<dim3(11, 16, 4), 256, 0, stream>>>(
            tbf, nullptr, 2048, WB, nullptr, EW, 2048, 1408, 2048,
            offsp, cntp, tok, 4 * g, h1buf, nullptr, 1408, nullptr, nullptr, nullptr);
        cvtT_k<0><<<dim3(22, 32, 4), 256, 0, stream>>>(w3 + (long long)g * 4 * EW, EW, WB, nullptr, EW, 2048, 1408);
        gemm_k<EPI_SILUMUL, false><<<dim3(11, 16, 4), 256, 0, stream>>>(
            tbf, nullptr, 2048, WB, nullptr, EW, 2048, 1408, 2048,
            offsp, cntp, tok, 4 * g, h1buf, nullptr, 1408, h1buf, nullptr, nullptr);
        cvtT_k<0><<<dim3(32, 22, 4), 256, 0, stream>>>(w2 + (long long)g * 4 * EW, EW, WB, nullptr, EW, 1408, 2048);
        gemm_k<EPI_BF16, false><<<dim3(16, 16, 4), 256, 0, stream>>>(
            h1buf, nullptr, 1408, WB, nullptr, EW, 2048, 2048, 1408,
            offsp, cntp, nullptr, 4 * g, eo, nullptr, 2048, nullptr, nullptr, nullptr);
    }

    // ---- shared expert ----
    cvtT_k<0><<<dim3(44, 32, 1), 256, 0, stream>>>(ws1, 0, WB, nullptr, 0, 2048, 2816);
    gemm_k<EPI_BF16, false><<<dim3(22, 16, 1), 256, 0, stream>>>(
        tbf, nullptr, 2048, WB, nullptr, 0, 2048, 2816, 2048,
        nullptr, nullptr, nullptr, 0, sh1, nullptr, 2816, nullptr, nullptr, nullptr);
    cvtT_k<0><<<dim3(44, 32, 1), 256, 0, stream>>>(ws3, 0, WB, nullptr, 0, 2048, 2816);
    gemm_k<EPI_SILUMUL, false><<<dim3(22, 16, 1), 256, 0, stream>>>(
        tbf, nullptr, 2048, WB, nullptr, 0, 2048, 2816, 2048,
        nullptr, nullptr, nullptr, 0, sh1, nullptr, 2816, sh1, nullptr, nullptr);
    cvtT_k<0><<<dim3(32, 44, 1), 256, 0, stream>>>(ws2, 0, WB, nullptr, 0, 2816, 2048);
    gemm_k<EPI_BF16, false><<<dim3(16, 16, 1), 256, 0, stream>>>(
        sh1, nullptr, 2816, WB, nullptr, 0, 2048, 2048, 2816,
        nullptr, nullptr, nullptr, 0, sobuf, nullptr, 2048, nullptr, nullptr, nullptr);

    final_k<<<4096, 256, 0, stream>>>(first, sobuf, eo, posm, wgl, (float*)d_out);
}